// Round 10
// baseline (490.354 us; speedup 1.0000x reference)
//
#include <hip/hip_runtime.h>
#include <cmath>

// Persistent weight-stationary LSTM decode. B=64, H=2048, steps=30.
// gates_t = W_sum @ h_t (t>=1, since x_t == h_t), W_hh @ h_0 at t=0.
// One block per CU (grid=256); weights live in LDS as fp16 MFMA A-frags.
//
// v14 = v13 topology + 16-wave block (1024 thr) + permuted W rows.
// v13 (load-issue pin) was the first confirmed win (335->290us k_lstm):
// the kernel is latency-bound on the per-step chain with only 2 waves/SIMD
// of TLP. This version doubles TLP (4 waves/SIMD):
//  - wave = (ks 0..3) x (nt 0..3): k-slice 512 x ONE n-tile; 16 pieces
//    (64 VGPR prefetch, fully pinnable under the 128-VGPR cap), 32 MFMAs.
//  - W rows PERMUTED at staging (gate=m16&3, unit=(mt?4:0)+(m16>>2)):
//    after the reduce each ks0-lane holds all 4 gates of units {q,q+4}
//    for one batch -> no 16-shfl exchange; pointwise = 2 units/lane;
//    publish = 1 shfl_xor(16) + one 4B agent store per lane.
//  - reduce: same 4-slice 2-round tree (2 barriers, 24KB red), per-nt
//    flags (1024). Summation order identical to v13 (same absmax).
// Sync scheme unchanged: agent-scope h stores, vmcnt(0), per-(nt,blk)
// flag, cacheable first-touch h reads (L2-amortized per XCD).

#define HID   2048
#define BATCH 64
#define G4    8192
#define NCU   256                 // persistent grid size == CU count
#define HGRP  (HID * BATCH / 8)   // half8 groups per h slot
#define NFLAGS 1024               // [nt][block]

typedef __attribute__((ext_vector_type(8))) _Float16 half8;
typedef __attribute__((ext_vector_type(4))) float f32x4;

// LDS layout (bytes):
//   [0,      131072)  Wlds : half8 frags [(mt*64+kt)*64+lane], PERMUTED rows
//   [131072, 155648)  red4 : f32x4 [24 rows][64 lanes]
//     rows 0-7: ks1 (nt*2+acc); rows 8-15: ks3; rows 16-23: ks2 partials
#define LDS_BYTES 155648

// ---- init: pack token -> h slot 0 (B-fragment layout), bsum, flags ----
__global__ void k_init(const float* __restrict__ token, const float* __restrict__ bih,
                       const float* __restrict__ bhh, half8* __restrict__ h0p,
                       float* __restrict__ bsum, unsigned* __restrict__ flags) {
    int g = blockIdx.x * 256 + threadIdx.x;          // [0, 16384)
    int l = g & 63, nt = (g >> 6) & 3, kt = g >> 8;
    int n = nt * 16 + (l & 15);
    int k0 = kt * 32 + (l >> 4) * 8;
    const float4* ps = (const float4*)(token + (size_t)n * HID + k0);
    float4 a = ps[0], b = ps[1];
    half8 v;
    v[0]=(_Float16)a.x; v[1]=(_Float16)a.y; v[2]=(_Float16)a.z; v[3]=(_Float16)a.w;
    v[4]=(_Float16)b.x; v[5]=(_Float16)b.y; v[6]=(_Float16)b.z; v[7]=(_Float16)b.w;
    h0p[g] = v;
    if (g < G4) bsum[g] = bih[g] + bhh[g];
    if (g < NFLAGS) flags[g] = 0u;
}

// ---- the persistent kernel: 1024 threads = 16 waves ----
__global__ __launch_bounds__(1024, 4)
void k_lstm(const float* __restrict__ wih, const float* __restrict__ whh,
            const float* __restrict__ bsum, const float* __restrict__ wout,
            _Float16* __restrict__ hbuf,     // (steps+1) slots, fragment layout
            float* __restrict__ ypart,       // [steps][NCU][64]
            unsigned* __restrict__ flags, int steps) {
    extern __shared__ char smem[];
    half8* Wlds = (half8*)smem;
    f32x4* red4 = (f32x4*)(smem + 131072);

    const int tid  = threadIdx.x;
    const int blk  = blockIdx.x;
    const int lane = tid & 63;
    const int w    = tid >> 6;        // wave 0..15
    const int nt   = w & 3;           // n-tile 0..3
    const int ks   = w >> 2;          // k-split slice 0..3 (512 k each)
    const int q    = lane >> 4;       // C-frag row quad 0..3
    const int col  = lane & 15;       // C-frag col (batch within tile)

    // prologue: stage W_hh with PERMUTED rows: A-frag row m16 within m-tile mt
    // holds gate (m16&3) of unit (mt?4:0)+(m16>>2).
    for (int idx = tid; idx < 2 * 64 * 64; idx += 1024) {
        int l = idx & 63, kt = (idx >> 6) & 63, mt = idx >> 12;
        int m16  = l & 15;
        int gate = m16 & 3;
        int uloc = (mt ? 4 : 0) + (m16 >> 2);
        int row  = gate * HID + blk * 8 + uloc;
        int colw = kt * 32 + (l >> 4) * 8;
        const float4* p = (const float4*)(whh + (size_t)row * HID + colw);
        float4 a = p[0], b = p[1];
        half8 v;
        v[0]=(_Float16)a.x; v[1]=(_Float16)a.y; v[2]=(_Float16)a.z; v[3]=(_Float16)a.w;
        v[4]=(_Float16)b.x; v[5]=(_Float16)b.y; v[6]=(_Float16)b.z; v[7]=(_Float16)b.w;
        Wlds[idx] = v;
    }

    // ks0-wave per-lane constants/state: units q (acc a0) and q+4 (acc a1),
    // batch nt*16+col.
    float bias0[4] = {0,0,0,0}, bias1[4] = {0,0,0,0};
    float wj0 = 0.0f, wj1 = 0.0f, c20 = 0.0f, c21 = 0.0f;
    if (ks == 0) {
        #pragma unroll
        for (int r = 0; r < 4; ++r) {
            bias0[r] = bsum[r * HID + blk * 8 + q];
            bias1[r] = bsum[r * HID + blk * 8 + 4 + q];
        }
        wj0 = wout[blk * 8 + q];
        wj1 = wout[blk * 8 + 4 + q];
    }
    __syncthreads();

    for (int t = 0; t < steps; ++t) {
        if (t) {
            // wave (ks,nt) consumes pieces (kt in slice, nt) from producers
            // blk' in [ks*64, ks*64+64). Lane li waits flags[nt][ks*64+li].
            while (__hip_atomic_load(&flags[nt * NCU + ks * 64 + lane],
                                     __ATOMIC_RELAXED, __HIP_MEMORY_SCOPE_AGENT)
                   < (unsigned)t)
                __builtin_amdgcn_s_sleep(1);
            asm volatile("" ::: "memory");   // no h loads hoisted above the spin
        }
        const half8* hp = (const half8*)(hbuf + (size_t)t * HID * BATCH);
        const int ktb = ks * 16;
        // ---- issue all 16 piece loads back-to-back, pinned above MFMA ----
        half8 bfr[16];
        #pragma unroll
        for (int kk = 0; kk < 16; ++kk)
            bfr[kk] = hp[((ktb + kk) * 4 + nt) * 64 + lane];
        __builtin_amdgcn_sched_barrier(0);   // loads may not sink below here
        f32x4 a0 = {0,0,0,0}, a1 = {0,0,0,0};
        #pragma unroll
        for (int kk = 0; kk < 16; ++kk) {
            int kt = ktb + kk;
            half8 av0 = Wlds[(kt) * 64 + lane];            // mt=0 (units 0-3)
            half8 av1 = Wlds[(64 + kt) * 64 + lane];       // mt=1 (units 4-7)
            a0 = __builtin_amdgcn_mfma_f32_16x16x32_f16(av0, bfr[kk], a0, 0, 0, 0);
            a1 = __builtin_amdgcn_mfma_f32_16x16x32_f16(av1, bfr[kk], a1, 0, 0, 0);
        }
        // ---- 2-barrier k-split reduce (4 slices, per nt) ----
        if (ks == 1) {
            red4[(nt * 2 + 0) * 64 + lane] = a0;
            red4[(nt * 2 + 1) * 64 + lane] = a1;
        } else if (ks == 3) {
            red4[(8 + nt * 2 + 0) * 64 + lane] = a0;
            red4[(8 + nt * 2 + 1) * 64 + lane] = a1;
        }
        __syncthreads();                                   // bar1
        if (ks == 0) {
            a0 += red4[(nt * 2 + 0) * 64 + lane];
            a1 += red4[(nt * 2 + 1) * 64 + lane];
        } else if (ks == 2) {
            a0 += red4[(8 + nt * 2 + 0) * 64 + lane];
            a1 += red4[(8 + nt * 2 + 1) * 64 + lane];
            red4[(16 + nt * 2 + 0) * 64 + lane] = a0;
            red4[(16 + nt * 2 + 1) * 64 + lane] = a1;
        }
        __syncthreads();                                   // bar2
        if (ks == 0) {
            a0 += red4[(16 + nt * 2 + 0) * 64 + lane];
            a1 += red4[(16 + nt * 2 + 1) * 64 + lane];
            // bias; then pointwise directly: a0 = gates(i,f,g,o) of unit q,
            // a1 = unit q+4, batch nt*16+col. No cross-lane exchange needed.
            #pragma unroll
            for (int r = 0; r < 4; ++r) { a0[r] += bias0[r]; a1[r] += bias1[r]; }
            float iv0 = 1.0f / (1.0f + __expf(-a0[0]));
            float fv0 = 1.0f / (1.0f + __expf(-a0[1]));
            float gv0 = 1.0f - 2.0f / (__expf(2.0f * a0[2]) + 1.0f);
            float ov0 = 1.0f / (1.0f + __expf(-a0[3]));
            c20 = fv0 * c20 + iv0 * gv0;
            float hv0 = ov0 * (1.0f - 2.0f / (__expf(2.0f * c20) + 1.0f));
            float iv1 = 1.0f / (1.0f + __expf(-a1[0]));
            float fv1 = 1.0f / (1.0f + __expf(-a1[1]));
            float gv1 = 1.0f - 2.0f / (__expf(2.0f * a1[2]) + 1.0f);
            float ov1 = 1.0f / (1.0f + __expf(-a1[3]));
            c21 = fv1 * c21 + iv1 * gv1;
            float hv1 = ov1 * (1.0f - 2.0f / (__expf(2.0f * c21) + 1.0f));
            if (t < steps - 1) {
                // pack units (q,q+4) as f16; one shfl pairs q<->q^1; each lane
                // stores ONE 4B word of the 16B piece (agent scope).
                union { _Float16 h; unsigned short u; } u0, u1;
                u0.h = (_Float16)hv0; u1.h = (_Float16)hv1;
                unsigned m = ((unsigned)u1.u << 16) | u0.u;
                unsigned x = __shfl_xor((int)m, 16);
                unsigned val; int widx;
                if ((q & 1) == 0) {    // word (units q, q+1) at byte 2q
                    val = ((x & 0xFFFFu) << 16) | (m & 0xFFFFu);
                    widx = q >> 1;
                } else {               // word (units q+3, q+4) at byte 8+2(q-1)
                    val = (m & 0xFFFF0000u) | (x >> 16);
                    widx = 2 + (q >> 1);
                }
                const size_t g = (size_t)((blk >> 2) * 4 + nt) * 64
                               + (blk & 3) * 16 + col;
                unsigned* p32 = (unsigned*)
                    (hbuf + (size_t)(t + 1) * HID * BATCH + g * 8);
                __hip_atomic_store(p32 + widx, val, __ATOMIC_RELAXED,
                                   __HIP_MEMORY_SCOPE_AGENT);
                asm volatile("s_waitcnt vmcnt(0)" ::: "memory");  // h visible
                if (lane == 0)
                    __hip_atomic_store(&flags[nt * NCU + blk], (unsigned)(t + 1),
                                       __ATOMIC_RELAXED, __HIP_MEMORY_SCOPE_AGENT);
            }
            // y partial (off the critical path, after flag release)
            float yp = wj0 * hv0 + wj1 * hv1;
            yp += __shfl_xor(yp, 16);          // sum over q pairs
            yp += __shfl_xor(yp, 32);          // all 4 q
            if (lane < 16)
                ypart[((size_t)t * NCU + blk) * 64 + nt * 16 + lane] = yp;
        }
        if (t == 0) {
            // upgrade Wlds in place: W_hh -> W_sum (+= W_ih), permuted rows;
            // must complete in ALL waves before step-1 MFMA -> barrier after.
            for (int idx = tid; idx < 2 * 64 * 64; idx += 1024) {
                int l = idx & 63, kt = (idx >> 6) & 63, mt = idx >> 12;
                int m16  = l & 15;
                int gate = m16 & 3;
                int uloc = (mt ? 4 : 0) + (m16 >> 2);
                int row  = gate * HID + blk * 8 + uloc;
                int colw = kt * 32 + (l >> 4) * 8;
                const float4* p = (const float4*)(wih + (size_t)row * HID + colw);
                float4 a = p[0], b = p[1];
                half8 v = Wlds[idx];
                v[0] = (_Float16)((float)v[0] + a.x); v[1] = (_Float16)((float)v[1] + a.y);
                v[2] = (_Float16)((float)v[2] + a.z); v[3] = (_Float16)((float)v[3] + a.w);
                v[4] = (_Float16)((float)v[4] + b.x); v[5] = (_Float16)((float)v[5] + b.y);
                v[6] = (_Float16)((float)v[6] + b.z); v[7] = (_Float16)((float)v[7] + b.w);
                Wlds[idx] = v;
            }
            __syncthreads();
        }
    }
}

// ---- final: out[b][t] = bout + sum over 256 CU partials ----
__global__ __launch_bounds__(512)
void k_yout(const float* __restrict__ ypart, const float* __restrict__ bout,
            float* __restrict__ out, int steps) {
    __shared__ float red[8][64];
    int t = blockIdx.x;
    int tid = threadIdx.x;
    int b = tid & 63, ch = tid >> 6;               // 8 chunks x 32 CUs
    const float* p = ypart + (size_t)t * NCU * 64 + b;
    float s = 0.0f;
    #pragma unroll 8
    for (int cu = ch * 32; cu < ch * 32 + 32; ++cu) s += p[(size_t)cu * 64];
    red[ch][b] = s;
    __syncthreads();
    if (tid < 64) {
        float r = bout[0];
        #pragma unroll
        for (int u = 0; u < 8; ++u) r += red[u][tid];
        out[(size_t)tid * steps + t] = r;
    }
}

extern "C" void kernel_launch(void* const* d_in, const int* in_sizes, int n_in,
                              void* d_out, int out_size, void* d_ws, size_t ws_size,
                              hipStream_t stream) {
    const float* token = (const float*)d_in[0];
    const float* wih   = (const float*)d_in[2];
    const float* whh   = (const float*)d_in[3];
    const float* bih   = (const float*)d_in[4];
    const float* bhh   = (const float*)d_in[5];
    const float* wout  = (const float*)d_in[6];
    const float* bout  = (const float*)d_in[7];
    float* out = (float*)d_out;
    const int steps = out_size / BATCH;            // 30

    char* ws = (char*)d_ws;
    size_t off = 0;
    auto carve = [&](size_t bytes) -> void* {
        void* p = ws + off;
        off = (off + bytes + 255) & ~(size_t)255;
        return p;
    };
    _Float16* hbuf  = (_Float16*)carve((size_t)(steps + 1) * HID * BATCH * 2); // ~8 MB
    float*    bsum  = (float*)carve((size_t)G4 * 4);                   // 32 KB
    float*    ypart = (float*)carve((size_t)steps * NCU * 64 * 4);     // ~2 MB
    unsigned* flags = (unsigned*)carve(NFLAGS * 4);

    hipFuncSetAttribute(reinterpret_cast<const void*>(&k_lstm),
                        hipFuncAttributeMaxDynamicSharedMemorySize, LDS_BYTES);

    k_init<<<dim3(HGRP / 256), dim3(256), 0, stream>>>(
        token, bih, bhh, (half8*)hbuf, bsum, flags);

    k_lstm<<<dim3(NCU), dim3(1024), LDS_BYTES, stream>>>(
        wih, whh, bsum, wout, hbuf, ypart, flags, steps);

    k_yout<<<dim3(steps), dim3(512), 0, stream>>>(ypart, bout, out, steps);
}

// Round 11
// 469.225 us; speedup vs baseline: 1.0450x; 1.0450x over previous
//
#include <hip/hip_runtime.h>
#include <cmath>

// Persistent weight-stationary LSTM decode. B=64, H=2048, steps=30.
// gates_t = W_sum @ h_t (t>=1, since x_t == h_t), W_hh @ h_0 at t=0.
// One block per CU (grid=256); weights live in LDS as fp16 MFMA A-frags.
//
// v15 = v14 with its two implementation bugs fixed (concept: 2x TLP via
// 16-wave block, h-traffic flat):
//  - amdgpu_waves_per_eu(4,4): forces the VGPR budget to 128 so the
//    16-piece load pin can materialize (v14's compiler chose 64 VGPRs ->
//    serialized loads, the v9 failure mode). CHECK: VGPR ~100-128.
//  - 8B publish restored (v14's 4B agent stores caused ~3x write
//    amplification, WRITE 9.8->32.8MB): permutation unit=2*(m16>>2)+mt
//    puts units (2q,2q+1) in-lane; 4B pack + shfl_xor(16) -> even-q
//    lanes store one 8B word. CHECK: WRITE back to ~10MB.
// Wave = (ks 0..3) x (nt 0..3): k-slice 512 x one n-tile, 16 pieces
// pinned above the MFMA loop (sched_barrier), 32 MFMAs, per-nt 2-round
// reduce (2 barriers, hazard-safe), in-lane pointwise in ks0 waves.
// Sync unchanged: agent h stores, vmcnt(0), per-(nt,blk) flag, cacheable
// first-touch h reads (XCD-L2 amortized).

#define HID   2048
#define BATCH 64
#define G4    8192
#define NCU   256                 // persistent grid size == CU count
#define HGRP  (HID * BATCH / 8)   // half8 groups per h slot
#define NFLAGS 1024               // [nt][block]

typedef __attribute__((ext_vector_type(8))) _Float16 half8;
typedef __attribute__((ext_vector_type(4))) float f32x4;

// LDS layout (bytes):
//   [0,      131072)  Wlds : half8 frags [(mt*64+kt)*64+lane], PERMUTED rows
//   [131072, 155648)  red4 : f32x4 [24 rows][64 lanes]
//     rows 0-7: ks1 (nt*2+acc); rows 8-15: ks3; rows 16-23: ks2 partials
#define LDS_BYTES 155648

// ---- init: pack token -> h slot 0 (B-fragment layout), bsum, flags ----
__global__ void k_init(const float* __restrict__ token, const float* __restrict__ bih,
                       const float* __restrict__ bhh, half8* __restrict__ h0p,
                       float* __restrict__ bsum, unsigned* __restrict__ flags) {
    int g = blockIdx.x * 256 + threadIdx.x;          // [0, 16384)
    int l = g & 63, nt = (g >> 6) & 3, kt = g >> 8;
    int n = nt * 16 + (l & 15);
    int k0 = kt * 32 + (l >> 4) * 8;
    const float4* ps = (const float4*)(token + (size_t)n * HID + k0);
    float4 a = ps[0], b = ps[1];
    half8 v;
    v[0]=(_Float16)a.x; v[1]=(_Float16)a.y; v[2]=(_Float16)a.z; v[3]=(_Float16)a.w;
    v[4]=(_Float16)b.x; v[5]=(_Float16)b.y; v[6]=(_Float16)b.z; v[7]=(_Float16)b.w;
    h0p[g] = v;
    if (g < G4) bsum[g] = bih[g] + bhh[g];
    if (g < NFLAGS) flags[g] = 0u;
}

// ---- the persistent kernel: 1024 threads = 16 waves, 4 waves/SIMD ----
__global__ __launch_bounds__(1024, 4) __attribute__((amdgpu_waves_per_eu(4, 4)))
void k_lstm(const float* __restrict__ wih, const float* __restrict__ whh,
            const float* __restrict__ bsum, const float* __restrict__ wout,
            _Float16* __restrict__ hbuf,     // (steps+1) slots, fragment layout
            float* __restrict__ ypart,       // [steps][NCU][64]
            unsigned* __restrict__ flags, int steps) {
    extern __shared__ char smem[];
    half8* Wlds = (half8*)smem;
    f32x4* red4 = (f32x4*)(smem + 131072);

    const int tid  = threadIdx.x;
    const int blk  = blockIdx.x;
    const int lane = tid & 63;
    const int w    = tid >> 6;        // wave 0..15
    const int nt   = w & 3;           // n-tile 0..3
    const int ks   = w >> 2;          // k-split slice 0..3 (512 k each)
    const int q    = lane >> 4;       // C-frag row quad 0..3
    const int col  = lane & 15;       // C-frag col (batch within tile)

    // prologue: stage W_hh with PERMUTED rows: A-frag row m16 within m-tile mt
    // holds gate (m16&3) of unit 2*(m16>>2)+mt.
    for (int idx = tid; idx < 2 * 64 * 64; idx += 1024) {
        int l = idx & 63, kt = (idx >> 6) & 63, mt = idx >> 12;
        int m16  = l & 15;
        int gate = m16 & 3;
        int uloc = 2 * (m16 >> 2) + mt;
        int row  = gate * HID + blk * 8 + uloc;
        int colw = kt * 32 + (l >> 4) * 8;
        const float4* p = (const float4*)(whh + (size_t)row * HID + colw);
        float4 a = p[0], b = p[1];
        half8 v;
        v[0]=(_Float16)a.x; v[1]=(_Float16)a.y; v[2]=(_Float16)a.z; v[3]=(_Float16)a.w;
        v[4]=(_Float16)b.x; v[5]=(_Float16)b.y; v[6]=(_Float16)b.z; v[7]=(_Float16)b.w;
        Wlds[idx] = v;
    }

    // ks0-wave per-lane constants/state: units 2q (acc a0) and 2q+1 (acc a1),
    // batch nt*16+col.
    float bias0[4] = {0,0,0,0}, bias1[4] = {0,0,0,0};
    float wj0 = 0.0f, wj1 = 0.0f, c20 = 0.0f, c21 = 0.0f;
    if (ks == 0) {
        #pragma unroll
        for (int r = 0; r < 4; ++r) {
            bias0[r] = bsum[r * HID + blk * 8 + 2 * q];
            bias1[r] = bsum[r * HID + blk * 8 + 2 * q + 1];
        }
        wj0 = wout[blk * 8 + 2 * q];
        wj1 = wout[blk * 8 + 2 * q + 1];
    }
    __syncthreads();

    for (int t = 0; t < steps; ++t) {
        if (t) {
            // wave (ks,nt) consumes pieces (kt in slice, nt) from producers
            // blk' in [ks*64, ks*64+64). Lane li waits flags[nt][ks*64+li].
            while (__hip_atomic_load(&flags[nt * NCU + ks * 64 + lane],
                                     __ATOMIC_RELAXED, __HIP_MEMORY_SCOPE_AGENT)
                   < (unsigned)t)
                __builtin_amdgcn_s_sleep(1);
            asm volatile("" ::: "memory");   // no h loads hoisted above the spin
        }
        const half8* hp = (const half8*)(hbuf + (size_t)t * HID * BATCH);
        const int ktb = ks * 16;
        // ---- issue all 16 piece loads back-to-back, pinned above MFMA ----
        half8 bfr[16];
        #pragma unroll
        for (int kk = 0; kk < 16; ++kk)
            bfr[kk] = hp[((ktb + kk) * 4 + nt) * 64 + lane];
        __builtin_amdgcn_sched_barrier(0);   // loads may not sink below here
        f32x4 a0 = {0,0,0,0}, a1 = {0,0,0,0};
        #pragma unroll
        for (int kk = 0; kk < 16; ++kk) {
            int kt = ktb + kk;
            half8 av0 = Wlds[(kt) * 64 + lane];            // mt=0 (even units)
            half8 av1 = Wlds[(64 + kt) * 64 + lane];       // mt=1 (odd units)
            a0 = __builtin_amdgcn_mfma_f32_16x16x32_f16(av0, bfr[kk], a0, 0, 0, 0);
            a1 = __builtin_amdgcn_mfma_f32_16x16x32_f16(av1, bfr[kk], a1, 0, 0, 0);
        }
        // ---- 2-barrier k-split reduce (4 slices, per nt) ----
        if (ks == 1) {
            red4[(nt * 2 + 0) * 64 + lane] = a0;
            red4[(nt * 2 + 1) * 64 + lane] = a1;
        } else if (ks == 3) {
            red4[(8 + nt * 2 + 0) * 64 + lane] = a0;
            red4[(8 + nt * 2 + 1) * 64 + lane] = a1;
        }
        __syncthreads();                                   // bar1
        if (ks == 0) {
            a0 += red4[(nt * 2 + 0) * 64 + lane];
            a1 += red4[(nt * 2 + 1) * 64 + lane];
        } else if (ks == 2) {
            a0 += red4[(8 + nt * 2 + 0) * 64 + lane];
            a1 += red4[(8 + nt * 2 + 1) * 64 + lane];
            red4[(16 + nt * 2 + 0) * 64 + lane] = a0;
            red4[(16 + nt * 2 + 1) * 64 + lane] = a1;
        }
        __syncthreads();                                   // bar2
        if (ks == 0) {
            a0 += red4[(16 + nt * 2 + 0) * 64 + lane];
            a1 += red4[(16 + nt * 2 + 1) * 64 + lane];
            // bias; pointwise in-lane: a0 = gates(i,f,g,o) of unit 2q,
            // a1 = unit 2q+1, batch nt*16+col.
            #pragma unroll
            for (int r = 0; r < 4; ++r) { a0[r] += bias0[r]; a1[r] += bias1[r]; }
            float iv0 = 1.0f / (1.0f + __expf(-a0[0]));
            float fv0 = 1.0f / (1.0f + __expf(-a0[1]));
            float gv0 = 1.0f - 2.0f / (__expf(2.0f * a0[2]) + 1.0f);
            float ov0 = 1.0f / (1.0f + __expf(-a0[3]));
            c20 = fv0 * c20 + iv0 * gv0;
            float hv0 = ov0 * (1.0f - 2.0f / (__expf(2.0f * c20) + 1.0f));
            float iv1 = 1.0f / (1.0f + __expf(-a1[0]));
            float fv1 = 1.0f / (1.0f + __expf(-a1[1]));
            float gv1 = 1.0f - 2.0f / (__expf(2.0f * a1[2]) + 1.0f);
            float ov1 = 1.0f / (1.0f + __expf(-a1[3]));
            c21 = fv1 * c21 + iv1 * gv1;
            float hv1 = ov1 * (1.0f - 2.0f / (__expf(2.0f * c21) + 1.0f));
            // pack units (2q,2q+1) -> 4B; xor16 merges q with q^1; even-q
            // lanes hold 8B = units [4*(q>>1), +4) -> ONE 8B agent store.
            union { _Float16 h; unsigned short u; } u0, u1;
            u0.h = (_Float16)hv0; u1.h = (_Float16)hv1;
            unsigned m32 = ((unsigned)u1.u << 16) | u0.u;
            unsigned x32 = __shfl_xor((int)m32, 16);
            if (t < steps - 1) {
                if ((q & 1) == 0) {
                    unsigned long long val =
                        ((unsigned long long)x32 << 32) | m32;
                    const size_t g = (size_t)((blk >> 2) * 4 + nt) * 64
                                   + (blk & 3) * 16 + col;
                    unsigned long long* dst = (unsigned long long*)
                        (hbuf + (size_t)(t + 1) * HID * BATCH + g * 8) + (q >> 1);
                    __hip_atomic_store(dst, val, __ATOMIC_RELAXED,
                                       __HIP_MEMORY_SCOPE_AGENT);
                }
                asm volatile("s_waitcnt vmcnt(0)" ::: "memory");  // h visible
                if (lane == 0)
                    __hip_atomic_store(&flags[nt * NCU + blk], (unsigned)(t + 1),
                                       __ATOMIC_RELAXED, __HIP_MEMORY_SCOPE_AGENT);
            }
            // y partial (off the critical path, after flag release)
            float yp = wj0 * hv0 + wj1 * hv1;
            yp += __shfl_xor(yp, 16);          // sum over q pairs
            yp += __shfl_xor(yp, 32);          // all 4 q
            if (lane < 16)
                ypart[((size_t)t * NCU + blk) * 64 + nt * 16 + lane] = yp;
        }
        if (t == 0) {
            // upgrade Wlds in place: W_hh -> W_sum (+= W_ih), permuted rows;
            // must complete in ALL waves before step-1 MFMA -> barrier after.
            for (int idx = tid; idx < 2 * 64 * 64; idx += 1024) {
                int l = idx & 63, kt = (idx >> 6) & 63, mt = idx >> 12;
                int m16  = l & 15;
                int gate = m16 & 3;
                int uloc = 2 * (m16 >> 2) + mt;
                int row  = gate * HID + blk * 8 + uloc;
                int colw = kt * 32 + (l >> 4) * 8;
                const float4* p = (const float4*)(wih + (size_t)row * HID + colw);
                float4 a = p[0], b = p[1];
                half8 v = Wlds[idx];
                v[0] = (_Float16)((float)v[0] + a.x); v[1] = (_Float16)((float)v[1] + a.y);
                v[2] = (_Float16)((float)v[2] + a.z); v[3] = (_Float16)((float)v[3] + a.w);
                v[4] = (_Float16)((float)v[4] + b.x); v[5] = (_Float16)((float)v[5] + b.y);
                v[6] = (_Float16)((float)v[6] + b.z); v[7] = (_Float16)((float)v[7] + b.w);
                Wlds[idx] = v;
            }
            __syncthreads();
        }
    }
}

// ---- final: out[b][t] = bout + sum over 256 CU partials ----
__global__ __launch_bounds__(512)
void k_yout(const float* __restrict__ ypart, const float* __restrict__ bout,
            float* __restrict__ out, int steps) {
    __shared__ float red[8][64];
    int t = blockIdx.x;
    int tid = threadIdx.x;
    int b = tid & 63, ch = tid >> 6;               // 8 chunks x 32 CUs
    const float* p = ypart + (size_t)t * NCU * 64 + b;
    float s = 0.0f;
    #pragma unroll 8
    for (int cu = ch * 32; cu < ch * 32 + 32; ++cu) s += p[(size_t)cu * 64];
    red[ch][b] = s;
    __syncthreads();
    if (tid < 64) {
        float r = bout[0];
        #pragma unroll
        for (int u = 0; u < 8; ++u) r += red[u][tid];
        out[(size_t)tid * steps + t] = r;
    }
}

extern "C" void kernel_launch(void* const* d_in, const int* in_sizes, int n_in,
                              void* d_out, int out_size, void* d_ws, size_t ws_size,
                              hipStream_t stream) {
    const float* token = (const float*)d_in[0];
    const float* wih   = (const float*)d_in[2];
    const float* whh   = (const float*)d_in[3];
    const float* bih   = (const float*)d_in[4];
    const float* bhh   = (const float*)d_in[5];
    const float* wout  = (const float*)d_in[6];
    const float* bout  = (const float*)d_in[7];
    float* out = (float*)d_out;
    const int steps = out_size / BATCH;            // 30

    char* ws = (char*)d_ws;
    size_t off = 0;
    auto carve = [&](size_t bytes) -> void* {
        void* p = ws + off;
        off = (off + bytes + 255) & ~(size_t)255;
        return p;
    };
    _Float16* hbuf  = (_Float16*)carve((size_t)(steps + 1) * HID * BATCH * 2); // ~8 MB
    float*    bsum  = (float*)carve((size_t)G4 * 4);                   // 32 KB
    float*    ypart = (float*)carve((size_t)steps * NCU * 64 * 4);     // ~2 MB
    unsigned* flags = (unsigned*)carve(NFLAGS * 4);

    hipFuncSetAttribute(reinterpret_cast<const void*>(&k_lstm),
                        hipFuncAttributeMaxDynamicSharedMemorySize, LDS_BYTES);

    k_init<<<dim3(HGRP / 256), dim3(256), 0, stream>>>(
        token, bih, bhh, (half8*)hbuf, bsum, flags);

    k_lstm<<<dim3(NCU), dim3(1024), LDS_BYTES, stream>>>(
        wih, whh, bsum, wout, hbuf, ypart, flags, steps);

    k_yout<<<dim3(steps), dim3(512), 0, stream>>>(ypart, bout, out, steps);
}